// Round 2
// baseline (111.026 us; speedup 1.0000x reference)
//
#include <hip/hip_runtime.h>
#include <math.h>

#define NUM_BINS 15
#define FL_EPS 1e-20f

// Fused single-kernel AdaFocal loss:
//  - one wave (64 lanes) per row, 2-row software pipeline (load row k+1
//    while reducing row k) to keep >4KB of loads in flight per wave
//  - row held entirely in registers (4 x float4 per lane); max and sum(exp)
//    via 6-step shfl_xor butterflies; inactive vector slots filled with -INF
//    so exp() of them is exactly 0 (no guards in the compute path)
//  - target logit x_t prefetched with the row loads (L2-hit)
//  - powf replaced by __expf(gm * __logf(base)); base in [eps, 2] so safe
//  - grid-wide sum fused via last-block-done: per-block partial + device
//    atomic ticket; last block reduces 2048 partials in fixed index order
//    (deterministic result regardless of which block finishes last)
__global__ __launch_bounds__(256) void adafocal_fused(
    const float* __restrict__ input, const int* __restrict__ target,
    const float* __restrict__ gammas, float* __restrict__ out,
    unsigned int* __restrict__ counter, float* __restrict__ partial,
    int N, int C)
{
    const int lane        = threadIdx.x & 63;
    const int waveInBlock = threadIdx.x >> 6;
    const int globalWave  = blockIdx.x * 4 + waveInBlock;
    const int totalWaves  = gridDim.x * 4;
    const int nvec = C >> 2;      // 250 for C=1000
    const int tail = C & 3;       // 0 for C=1000

    float acc = 0.0f;

    auto loadRow = [&](int row, float4 (&v)[4], float& tl, float& xt) {
        const float* rowp = input + (size_t)row * (size_t)C;
        #pragma unroll
        for (int it = 0; it < 4; ++it) {
            int j = lane + it * 64;
            if (j < nvec) v[it] = reinterpret_cast<const float4*>(rowp)[j];
            else          v[it] = make_float4(-INFINITY, -INFINITY, -INFINITY, -INFINITY);
        }
        tl = (lane < tail) ? rowp[(nvec << 2) + lane] : -INFINITY;
        int t = target[row];          // wave-uniform
        xt = rowp[t];                 // issued with the row loads; L2-hit
    };

    auto computeRow = [&](const float4 (&v)[4], float tl, float xt) {
        float mx = tl;
        #pragma unroll
        for (int it = 0; it < 4; ++it)
            mx = fmaxf(fmaxf(mx, fmaxf(v[it].x, v[it].y)), fmaxf(v[it].z, v[it].w));
        #pragma unroll
        for (int off = 32; off >= 1; off >>= 1)
            mx = fmaxf(mx, __shfl_xor(mx, off, 64));

        float s = __expf(tl - mx);    // 0 when tl == -INF
        #pragma unroll
        for (int it = 0; it < 4; ++it)
            s += __expf(v[it].x - mx) + __expf(v[it].y - mx)
               + __expf(v[it].z - mx) + __expf(v[it].w - mx);
        #pragma unroll
        for (int off = 32; off >= 1; off >>= 1)
            s += __shfl_xor(s, off, 64);

        if (lane == 0) {
            float logZ  = mx + __logf(s);
            float logpt = xt - logZ;
            float pt    = __expf(logpt);
            int bin = (int)(pt * (float)NUM_BINS);
            bin = min(max(bin, 0), NUM_BINS - 1);
            float g  = gammas[bin];
            float gs = (g > 0.0f) ? 1.0f : ((g < 0.0f) ? -1.0f : 0.0f);
            float base = 1.0f - gs * pt + FL_EPS;       // in [eps, 2]
            acc += -__expf(fabsf(g) * __logf(base)) * logpt;
        }
    };

    // ---- 2-deep pipelined row loop ----
    {
        float4 A[4], B[4];
        float tA, xA, tB, xB;
        int r = globalWave;
        if (r < N) {
            loadRow(r, A, tA, xA);
            for (;;) {
                int rB = r + totalWaves;
                bool hasB = rB < N;
                if (hasB) loadRow(rB, B, tB, xB);      // B loads fly under A's reduce
                computeRow(A, tA, xA);
                if (!hasB) break;
                int rA2 = rB + totalWaves;
                bool hasA2 = rA2 < N;
                if (hasA2) loadRow(rA2, A, tA, xA);    // next A under B's reduce
                computeRow(B, tB, xB);
                if (!hasA2) break;
                r = rA2;
            }
        }
    }

    // ---- block reduce + last-block-done grid reduce ----
    __shared__ float waveSum[4];
    __shared__ bool  amLast;
    if (lane == 0) waveSum[waveInBlock] = acc;
    __syncthreads();
    if (threadIdx.x == 0) {
        float bsum = waveSum[0] + waveSum[1] + waveSum[2] + waveSum[3];
        partial[blockIdx.x] = bsum;
        __threadfence();                               // release partial
        unsigned int ticket = atomicAdd(counter, 1u);  // device-scope
        amLast = (ticket == (unsigned int)gridDim.x - 1u);
    }
    __syncthreads();
    if (amLast) {
        __threadfence();                               // acquire partials
        float s = 0.0f;
        for (int i = threadIdx.x; i < gridDim.x; i += 256) s += partial[i];
        #pragma unroll
        for (int off = 32; off >= 1; off >>= 1)
            s += __shfl_xor(s, off, 64);
        if (lane == 0) waveSum[waveInBlock] = s;
        __syncthreads();
        if (threadIdx.x == 0)
            out[0] = waveSum[0] + waveSum[1] + waveSum[2] + waveSum[3];
    }
}

extern "C" void kernel_launch(void* const* d_in, const int* in_sizes, int n_in,
                              void* d_out, int out_size, void* d_ws, size_t ws_size,
                              hipStream_t stream) {
    const float* input  = (const float*)d_in[0];
    const int*   target = (const int*)d_in[1];
    const float* gammas = (const float*)d_in[2];
    float* out = (float*)d_out;

    const int N = in_sizes[1];             // 65536 rows
    const int C = in_sizes[0] / N;         // 1000 classes
    const int BLOCKS = 2048;               // 8 blocks/CU nominal

    unsigned int* counter = (unsigned int*)d_ws;               // 1 u32, zeroed per call
    float*        partial = (float*)((char*)d_ws + 64);        // 2048 floats

    hipMemsetAsync(d_ws, 0, 64, stream);   // ticket counter must start at 0 each call
    adafocal_fused<<<BLOCKS, 256, 0, stream>>>(input, target, gammas, out,
                                               counter, partial, N, C);
}